// Round 2
// baseline (57.283 us; speedup 1.0000x reference)
//
#include <hip/hip_runtime.h>
#include <hip/hip_bf16.h>

#define D 128
#define Nn 512
#define Bb 2

typedef __bf16 bf16x8_t __attribute__((ext_vector_type(8)));
typedef float f32x4_t __attribute__((ext_vector_type(4)));

// ---------------------------------------------------------------------------
// Kernel 1: A[b,i,e] = (dom*evo)@W1[:D] + b1 ;  C[b,i,e] = (dom*evo)@W1[D:]
// One block per 4 consecutive (b,i) flats: stage 4 g-vectors in LDS, share the
// W1 column stream across them (4 fma per load).
// ---------------------------------------------------------------------------
__global__ __launch_bounds__(256)
void precompute_ac(const float* __restrict__ dom, const float* __restrict__ evo,
                   const float* __restrict__ W1, const float* __restrict__ b1,
                   float* __restrict__ A, float* __restrict__ C) {
    const int t = threadIdx.x;
    const int base = blockIdx.x * 4;               // 4 (b,i) rows per block
    __shared__ float g4[4][D];
#pragma unroll
    for (int it = 0; it < 2; ++it) {
        int idx = it * 256 + t;
        int r = idx >> 7, c = idx & 127;
        size_t off = (size_t)(base + r) * D + c;
        g4[r][c] = dom[off] * evo[off];
    }
    __syncthreads();
    const int half = t >> 7;                       // 0 -> A, 1 -> C
    const int e = t & 127;
    const float* Wp = W1 + half * D * D;
    float a0 = 0.f, a1 = 0.f, a2 = 0.f, a3 = 0.f;
#pragma unroll 8
    for (int dp = 0; dp < D; ++dp) {
        float w = Wp[dp * D + e];                  // coalesced over e
        a0 = fmaf(g4[0][dp], w, a0);               // g4[.][dp] = LDS broadcast
        a1 = fmaf(g4[1][dp], w, a1);
        a2 = fmaf(g4[2][dp], w, a2);
        a3 = fmaf(g4[3][dp], w, a3);
    }
    if (half == 0) {
        float bb = b1[e];
        A[(size_t)(base + 0) * D + e] = a0 + bb;
        A[(size_t)(base + 1) * D + e] = a1 + bb;
        A[(size_t)(base + 2) * D + e] = a2 + bb;
        A[(size_t)(base + 3) * D + e] = a3 + bb;
    } else {
        C[(size_t)(base + 0) * D + e] = a0;
        C[(size_t)(base + 1) * D + e] = a1;
        C[(size_t)(base + 2) * D + e] = a2;
        C[(size_t)(base + 3) * D + e] = a3;
    }
}

// ---------------------------------------------------------------------------
// Kernel 2: block = (b, i-group-of-4, j-chunk-of-64), triangle-skipped.
// 4 waves; wave w handles i = 4g + w over all 4 j-tiles of the chunk.
// LDS: C chunk [64][128] f32, XOR-swizzled in 16B granules (col4 ^= row&7)
// so ds_read_b128 spreads 8 lanes per bank-quad (2-way = free).
// MFMA 16x16x32 bf16: A-frag rows = j, B-frag cols = e, C/D row=(q*4+r) col=m.
// ---------------------------------------------------------------------------
__global__ __launch_bounds__(256, 4)
void coevo_main(const float* __restrict__ A, const float* __restrict__ C,
                const float* __restrict__ W2, const float* __restrict__ b2,
                const float* __restrict__ W3, const float* __restrict__ b3,
                float* __restrict__ out) {
    const int tid  = threadIdx.x;
    const int wave = tid >> 6;
    const int lane = tid & 63;
    const int m = lane & 15;
    const int q = lane >> 4;

    const int blk   = blockIdx.x;                  // b*1024 + g*8 + chunk
    const int b     = blk >> 10;
    const int g     = (blk >> 3) & 127;
    const int chunk = blk & 7;
    if (chunk < (g >> 4)) return;                  // chunk entirely below diagonal

    const int i = g * 4 + wave;

    __shared__ float cs[64 * 128];                 // 32 KB, swizzled

    // ---- stage the 64-row C chunk into LDS (swizzled)
    const float* Cb = C + ((size_t)b * Nn + (size_t)chunk * 64) * D;
#pragma unroll
    for (int it = 0; it < 8; ++it) {
        int f  = it * 256 + tid;                   // float4 index 0..2047
        int r  = f >> 5;
        int c4 = f & 31;
        f32x4_t v = *(const f32x4_t*)(Cb + (size_t)f * 4);
        *(f32x4_t*)(&cs[r * 128 + (c4 ^ (r & 7)) * 4]) = v;
    }

    // ---- per-lane A row (b1 folded): ab[kk*8+e] = A[b,i, kk*32 + q*8 + e]
    float ab[32];
    {
        const float* Ap = A + ((size_t)(b * Nn + i)) * D + q * 8;
#pragma unroll
        for (int kk = 0; kk < 4; ++kk) {
            f32x4_t v0 = *(const f32x4_t*)(Ap + kk * 32);
            f32x4_t v1 = *(const f32x4_t*)(Ap + kk * 32 + 4);
            ab[kk * 8 + 0] = v0[0]; ab[kk * 8 + 1] = v0[1];
            ab[kk * 8 + 2] = v0[2]; ab[kk * 8 + 3] = v0[3];
            ab[kk * 8 + 4] = v1[0]; ab[kk * 8 + 5] = v1[1];
            ab[kk * 8 + 6] = v1[2]; ab[kk * 8 + 7] = v1[3];
        }
    }

    // ---- W2 B-fragments: w2f[et][kk][e] = W2[kk*32+q*8+e][et*16+m]  (L2-hot)
    bf16x8_t w2f[4][4];
#pragma unroll
    for (int et = 0; et < 4; ++et) {
#pragma unroll
        for (int kk = 0; kk < 4; ++kk) {
            bf16x8_t w;
#pragma unroll
            for (int e = 0; e < 8; ++e) {
                int k = kk * 32 + q * 8 + e;
                w[e] = (__bf16)W2[k * 64 + et * 16 + m];
            }
            w2f[et][kk] = w;
        }
    }

    // ---- epilogue constants for this lane's columns e = et*16 + m
    float b2v[4], w3v[4];
#pragma unroll
    for (int et = 0; et < 4; ++et) {
        b2v[et] = b2[et * 16 + m];
        w3v[et] = W3[et * 16 + m];
    }
    const float b3s = b3[0];

    __syncthreads();

#pragma unroll
    for (int jt = 0; jt < 4; ++jt) {
        if (chunk * 64 + jt * 16 + 15 < i) continue;   // tile entirely below diag
        const int jrow = jt * 16 + m;                  // this lane's j row
        const float* cr = &cs[jrow * 128];
        const int sw = m & 7;                          // swizzle key (row&7)

        // ---- build H fragments: h = relu(a + c)  (b1 folded into a)
        bf16x8_t af[4];
#pragma unroll
        for (int kk = 0; kk < 4; ++kk) {
            const int c4a = kk * 8 + q * 2;
            f32x4_t c0 = *(const f32x4_t*)(cr + ((c4a    ) ^ sw) * 4);
            f32x4_t c1 = *(const f32x4_t*)(cr + ((c4a + 1) ^ sw) * 4);
            bf16x8_t h;
            h[0] = (__bf16)fmaxf(ab[kk * 8 + 0] + c0[0], 0.f);
            h[1] = (__bf16)fmaxf(ab[kk * 8 + 1] + c0[1], 0.f);
            h[2] = (__bf16)fmaxf(ab[kk * 8 + 2] + c0[2], 0.f);
            h[3] = (__bf16)fmaxf(ab[kk * 8 + 3] + c0[3], 0.f);
            h[4] = (__bf16)fmaxf(ab[kk * 8 + 4] + c1[0], 0.f);
            h[5] = (__bf16)fmaxf(ab[kk * 8 + 5] + c1[1], 0.f);
            h[6] = (__bf16)fmaxf(ab[kk * 8 + 6] + c1[2], 0.f);
            h[7] = (__bf16)fmaxf(ab[kk * 8 + 7] + c1[3], 0.f);
            af[kk] = h;
        }

        // ---- GEMM: [16j x 128k] @ [128k x 64e]
        f32x4_t acc[4];
#pragma unroll
        for (int et = 0; et < 4; ++et) {
            f32x4_t a = {0.f, 0.f, 0.f, 0.f};
#pragma unroll
            for (int kk = 0; kk < 4; ++kk)
                a = __builtin_amdgcn_mfma_f32_16x16x32_bf16(af[kk], w2f[et][kk], a, 0, 0, 0);
            acc[et] = a;
        }

        // ---- epilogue: relu(+b2), dot W3 over e, 16-lane reduce, sigmoid
        float part[4];
#pragma unroll
        for (int r = 0; r < 4; ++r) {
            float p = 0.f;
#pragma unroll
            for (int et = 0; et < 4; ++et) {
                float h2 = fmaxf(acc[et][r] + b2v[et], 0.f);
                p = fmaf(h2, w3v[et], p);
            }
            part[r] = p;
        }
#pragma unroll
        for (int off = 8; off >= 1; off >>= 1) {
#pragma unroll
            for (int r = 0; r < 4; ++r)
                part[r] += __shfl_xor(part[r], off, 64);
        }

        if (m == 0) {
            const int j0 = chunk * 64 + jt * 16 + q * 4;
#pragma unroll
            for (int r = 0; r < 4; ++r) {
                const int j = j0 + r;
                if (j > i) {
                    float sv = 1.f / (1.f + expf(-(part[r] + b3s)));
                    out[((size_t)b * Nn + i) * Nn + j] = sv;
                    out[((size_t)b * Nn + j) * Nn + i] = sv;
                } else if (j == i) {
                    out[((size_t)b * Nn + i) * Nn + j] = 0.f;
                }
            }
        }
    }
}

extern "C" void kernel_launch(void* const* d_in, const int* in_sizes, int n_in,
                              void* d_out, int out_size, void* d_ws, size_t ws_size,
                              hipStream_t stream) {
    const float* dom = (const float*)d_in[0];
    const float* evo = (const float*)d_in[1];
    const float* W1  = (const float*)d_in[2];
    const float* b1  = (const float*)d_in[3];
    const float* W2  = (const float*)d_in[4];
    const float* b2  = (const float*)d_in[5];
    const float* W3  = (const float*)d_in[6];
    const float* b3  = (const float*)d_in[7];
    float* out = (float*)d_out;

    float* A = (float*)d_ws;                       // [B][N][D] f32
    float* C = A + (size_t)Bb * Nn * D;            // [B][N][D] f32

    precompute_ac<<<Bb * Nn / 4, 256, 0, stream>>>(dom, evo, W1, b1, A, C);
    coevo_main<<<Bb * 128 * 8, 256, 0, stream>>>(A, C, W2, b2, W3, b3, out);
}